// Round 7
// baseline (544.792 us; speedup 1.0000x reference)
//
#include <hip/hip_runtime.h>
#include <hip/hip_bf16.h>

typedef _Float16 f16;
typedef _Float16 f16x4 __attribute__((ext_vector_type(4)));
typedef _Float16 f16x8 __attribute__((ext_vector_type(8)));
typedef float f32x4 __attribute__((ext_vector_type(4)));

#define B_    64
#define T_    576
#define C_    1024
#define KDIM  576     // K extent / row stride of all staged matrices
#define MPAD  640     // padded row count for MT/MiT buffers
#define AROWS 1280    // stacked A matrix rows: [M_L ; G], padded
#define BK    64      // K-tile for the 256^2 GEMM
#define NT    9       // KDIM / BK

// async global->LDS, 16B per lane; LDS dest must be linear (base + lane*16)
__device__ __forceinline__ void gload_lds16(const void* g, void* l) {
  __builtin_amdgcn_global_load_lds(
      (__attribute__((address_space(1))) void*)(void*)g,
      (__attribute__((address_space(3))) void*)l, 16, 0, 0);
}

// ---------------- matrix generation (replicates jnp float32 op order) -------
// y=0: Astk rows [0,L) = M[k][t] f16; rows [L,AROWS) zeroed (G fills [L,L+640))
// y=1: MT  [640][576] = M[l][t] at [t][l], hi/lo   (zero rows t>=576)
// y=2: MiT [640][576] = Mi[l][k] at [k][l], hi/lo  (zero outside k<L,l<L)
__global__ void gen_mats(f16* __restrict__ Astk,
                         f16* __restrict__ MTh, f16* __restrict__ MTl,
                         f16* __restrict__ MiTh, f16* __restrict__ MiTl, int L) {
  int idx = blockIdx.x * 256 + threadIdx.x;
  const float pif = 3.14159265358979323846f;  // f32-rounded pi, as jnp uses
  float v = 0.0f;
  if (blockIdx.y == 0) {
    if (idx >= AROWS * KDIM) return;
    int row = idx / KDIM;
    int col = idx - row * KDIM;
    if (row < L) {  // M[k][t], k=row<576, t=col
      float a = pif * (float)(2 * col + 1);
      a = a * (float)row;
      a = a / 1152.0f;
      float s = (row == 0) ? sqrtf((float)(1.0 / 576.0)) : sqrtf((float)(2.0 / 576.0));
      v = s * cosf(a);
    }
    Astk[idx] = (f16)v;  // rows >= L zeroed here; gemm_G overwrites [L, L+640)
  } else if (blockIdx.y == 1) {
    if (idx >= MPAD * KDIM) return;
    int row = idx / KDIM;
    int col = idx - row * KDIM;
    if (row < T_) {  // MT[t][l] = M[l][t], t=row, l=col
      float a = pif * (float)(2 * row + 1);
      a = a * (float)col;
      a = a / 1152.0f;
      float s = (col == 0) ? sqrtf((float)(1.0 / 576.0)) : sqrtf((float)(2.0 / 576.0));
      v = s * cosf(a);
    }
    f16 h = (f16)v;
    MTh[idx] = h;
    MTl[idx] = (f16)(v - (float)h);
  } else {
    if (idx >= MPAD * KDIM) return;
    int row = idx / KDIM;
    int col = idx - row * KDIM;
    if (row < L && col < L) {  // MiT[k][l] = Mi[l][k]; dct_mat(L)
      float a = pif * (float)(2 * row + 1);
      a = a * (float)col;
      a = a / (float)(2 * L);
      float s = (col == 0) ? sqrtf((float)(1.0 / (double)L))
                           : sqrtf((float)(2.0 / (double)L));
      v = s * cosf(a);
    }
    f16 h = (f16)v;
    MiTh[idx] = h;
    MiTl[idx] = (f16)(v - (float)h);
  }
}

// ---------------- G = MiT . M_L via hi/lo split MFMA (f32-accurate) ---------
// D[m=t][n=k] = sum_l MT[t][l]*MiT[k][l]  ->  store into Astk row (L+k), col t
__global__ void gemm_G(const f16* __restrict__ gAh, const f16* __restrict__ gAl,
                       const f16* __restrict__ gBh, const f16* __restrict__ gBl,
                       f16* __restrict__ Astk, int L) {
  __shared__ __align__(16) f16 sAh[128 * 32];
  __shared__ __align__(16) f16 sAl[128 * 32];
  __shared__ __align__(16) f16 sBh[128 * 32];
  __shared__ __align__(16) f16 sBl[128 * 32];
  const int tid = threadIdx.x, lane = tid & 63, wid = tid >> 6;
  const int m0 = blockIdx.y * 128, n0 = blockIdx.x * 128;
  const int wr = wid >> 1, wc = wid & 1;
  const int l15 = lane & 15, lg = lane >> 4;

  f32x4 acc[4][4];
#pragma unroll
  for (int i = 0; i < 4; ++i)
#pragma unroll
    for (int j = 0; j < 4; ++j) acc[i][j] = (f32x4){0.f, 0.f, 0.f, 0.f};

  for (int kt = 0; kt < KDIM; kt += 32) {
    __syncthreads();
#pragma unroll
    for (int it = 0; it < 2; ++it) {
      const int o = it * 4096 + tid * 16;
      const int r = o >> 6, cb = o & 63;
      gload_lds16((const char*)gAh + ((size_t)(m0 + r) * KDIM + kt) * 2 + cb, (char*)sAh + o);
      gload_lds16((const char*)gAl + ((size_t)(m0 + r) * KDIM + kt) * 2 + cb, (char*)sAl + o);
      gload_lds16((const char*)gBh + ((size_t)(n0 + r) * KDIM + kt) * 2 + cb, (char*)sBh + o);
      gload_lds16((const char*)gBl + ((size_t)(n0 + r) * KDIM + kt) * 2 + cb, (char*)sBl + o);
    }
    __syncthreads();

    f16x8 ah[4], al[4], bh[4], bl[4];
#pragma unroll
    for (int i = 0; i < 4; ++i) {
      const int ra = (wr * 64 + i * 16 + l15) * 32 + lg * 8;
      ah[i] = *(const f16x8*)&sAh[ra];
      al[i] = *(const f16x8*)&sAl[ra];
      const int rb = (wc * 64 + i * 16 + l15) * 32 + lg * 8;
      bh[i] = *(const f16x8*)&sBh[rb];
      bl[i] = *(const f16x8*)&sBl[rb];
    }
#pragma unroll
    for (int i = 0; i < 4; ++i)
#pragma unroll
      for (int j = 0; j < 4; ++j) {
        acc[i][j] = __builtin_amdgcn_mfma_f32_16x16x32_f16(ah[i], bh[j], acc[i][j], 0, 0, 0);
        acc[i][j] = __builtin_amdgcn_mfma_f32_16x16x32_f16(ah[i], bl[j], acc[i][j], 0, 0, 0);
        acc[i][j] = __builtin_amdgcn_mfma_f32_16x16x32_f16(al[i], bh[j], acc[i][j], 0, 0, 0);
      }
  }

#pragma unroll
  for (int i = 0; i < 4; ++i) {
    const int t4 = m0 + wr * 64 + i * 16 + lg * 4;  // 4 consecutive t
#pragma unroll
    for (int j = 0; j < 4; ++j) {
      const int k = n0 + wc * 64 + j * 16 + l15;
      if (t4 < T_) {
        f32x4 v = acc[i][j];
        f16x4 hv;
#pragma unroll
        for (int r = 0; r < 4; ++r) hv[r] = (f16)v[r];
        *(f16x4*)&Astk[(size_t)(L + k) * KDIM + t4] = hv;
      }
    }
  }
}

// ---------------- transpose + fp32 -> fp16 ----------------------------------
// x[b][t][c] (f32) -> XT[b][c][t] (f16)
__global__ void transpose_f16(const float* __restrict__ x, f16* __restrict__ XT) {
  __shared__ float tile[64][65];
  const int b = blockIdx.z;
  const int t0 = blockIdx.y * 64, c0 = blockIdx.x * 64;
  const int i = threadIdx.x;
  const float* xp = x + ((size_t)b * T_ + t0) * C_ + c0;
  const int lrow = i >> 4, lcq = (i & 15) * 4;
#pragma unroll
  for (int p = 0; p < 4; ++p) {
    int r = p * 16 + lrow;
    float4 v = *(const float4*)&xp[(size_t)r * C_ + lcq];
    tile[r][lcq + 0] = v.x; tile[r][lcq + 1] = v.y;
    tile[r][lcq + 2] = v.z; tile[r][lcq + 3] = v.w;
  }
  __syncthreads();
  const int tg = (i & 7) * 8, cl = i >> 3;  // cl in [0,32)
#pragma unroll
  for (int h = 0; h < 2; ++h) {
    int c = cl + h * 32;
    f16x8 o;
#pragma unroll
    for (int u = 0; u < 8; ++u) o[u] = (f16)tile[tg + u][c];
    *(f16x8*)&XT[((size_t)b * C_ + c0 + c) * T_ + t0 + tg] = o;
  }
}

// ---------------- 256x256-tile 8-wave deep-pipelined GEMM -------------------
// D[m][n] = sum_k Astk[m][k] * XT_b[n][k];  m = stacked row (trunc|state)
// T2 swizzle: lds byte col ^= (row&7)<<4 (write via pre-swizzled global src).
// T4: counted vmcnt(8) per K-tile (drain 0 only on the last).  T5: setprio.
__global__ __launch_bounds__(512, 2)
void gemm256(const f16* __restrict__ gA, const f16* __restrict__ gXT,
             float* __restrict__ out_trunc, float* __restrict__ out_state,
             int L) {
  __shared__ __align__(16) f16 ldsA[2][256 * BK];  // 32KB x2
  __shared__ __align__(16) f16 ldsB[2][256 * BK];  // 32KB x2

  const int tid = threadIdx.x;
  const int lane = tid & 63, wid = tid >> 6;  // 8 waves
  const int wm = wid >> 2, wn = wid & 3;      // 2 (M) x 4 (N)
  const int b = blockIdx.z;
  const int m0 = blockIdx.y * 256, n0 = blockIdx.x * 256;
  const int l15 = lane & 15, lg = lane >> 4;
  const f16* gB = gXT + (size_t)b * C_ * KDIM;

  // ---- staging: linear LDS dest (lane*16B), pre-swizzled global source ----
  // lane's linear byte off o: row=o>>7, colByte=o&127; src col = colByte ^ ((row&7)<<4)
  int srow[4], scol[4];
#pragma unroll
  for (int i = 0; i < 4; ++i) {
    const int o = i * 8192 + tid * 16;
    srow[i] = o >> 7;
    scol[i] = (o & 127) ^ ((srow[i] & 7) << 4);
  }

#define STAGE(tile_, buf_)                                                        \
  {                                                                               \
    const int ktb_ = (tile_) * (BK * 2);                                          \
    _Pragma("unroll") for (int i = 0; i < 4; ++i) {                               \
      gload_lds16((const char*)gA + (size_t)(m0 + srow[i]) * (KDIM * 2) + ktb_ +  \
                      scol[i],                                                    \
                  (char*)&ldsA[buf_][0] + i * 8192 + tid * 16);                   \
    }                                                                             \
    _Pragma("unroll") for (int i = 0; i < 4; ++i) {                               \
      gload_lds16((const char*)gB + (size_t)(n0 + srow[i]) * (KDIM * 2) + ktb_ +  \
                      scol[i],                                                    \
                  (char*)&ldsB[buf_][0] + i * 8192 + tid * 16);                   \
    }                                                                             \
  }

  f32x4 acc[8][4];
#pragma unroll
  for (int i = 0; i < 8; ++i)
#pragma unroll
    for (int j = 0; j < 4; ++j) acc[i][j] = (f32x4){0.f, 0.f, 0.f, 0.f};

  // per-lane swizzled read cols (elements): ((ks*64+lg*16)^((l15&7)<<4))/2
  const int xorv = (l15 & 7) << 4;
  const int eac0 = ((0 * 64 + lg * 16) ^ xorv) >> 1;
  const int eac1 = ((1 * 64 + lg * 16) ^ xorv) >> 1;
  const int arb = wm * 128 + l15;  // A row base (within tile)
  const int brb = wn * 64 + l15;   // B row base

  STAGE(0, 0);
  STAGE(1, 1);

  for (int t = 0; t < NT; ++t) {
    if (t == NT - 1) {
      asm volatile("s_waitcnt vmcnt(0)" ::: "memory");
    } else {
      asm volatile("s_waitcnt vmcnt(8)" ::: "memory");
    }
    asm volatile("s_barrier" ::: "memory");
    const f16* sA = &ldsA[t & 1][0];
    const f16* sB = &ldsB[t & 1][0];

    // B fragments for the whole K-tile (wave's 4 n-frags x 2 k-slices)
    f16x8 bf[4][2];
#pragma unroll
    for (int nf = 0; nf < 4; ++nf) {
      bf[nf][0] = *(const f16x8*)&sB[(brb + nf * 16) * BK + eac0];
      bf[nf][1] = *(const f16x8*)&sB[(brb + nf * 16) * BK + eac1];
    }
    // 4 phases: 2 m-frags each, 16 MFMA per phase
#pragma unroll
    for (int ph = 0; ph < 4; ++ph) {
      f16x8 af[2][2];
#pragma unroll
      for (int mf = 0; mf < 2; ++mf) {
        const int ar = (arb + ph * 32 + mf * 16) * BK;
        af[mf][0] = *(const f16x8*)&sA[ar + eac0];
        af[mf][1] = *(const f16x8*)&sA[ar + eac1];
      }
      __builtin_amdgcn_s_setprio(1);
#pragma unroll
      for (int ks = 0; ks < 2; ++ks)
#pragma unroll
        for (int mf = 0; mf < 2; ++mf)
#pragma unroll
          for (int nf = 0; nf < 4; ++nf)
            acc[ph * 2 + mf][nf] = __builtin_amdgcn_mfma_f32_16x16x32_f16(
                af[mf][ks], bf[nf][ks], acc[ph * 2 + mf][nf], 0, 0, 0);
      __builtin_amdgcn_s_setprio(0);
    }

    // ensure every ds_read of buf[t&1] has RETURNED before releasing it
    asm volatile("s_waitcnt lgkmcnt(0)" ::: "memory");
    asm volatile("s_barrier" ::: "memory");  // all waves done reading buf[t&1]
    if (t + 2 < NT) STAGE(t + 2, t & 1);
  }

  // ---------------- epilogue: rows < L -> trunc, [L,2L) -> state ------------
  const int L2 = 2 * L;
#pragma unroll
  for (int mi = 0; mi < 8; ++mi) {
    const int kk0 = m0 + wm * 128 + mi * 16 + lg * 4;
#pragma unroll
    for (int nf = 0; nf < 4; ++nf) {
      const int c = n0 + wn * 64 + nf * 16 + l15;
      f32x4 v = acc[mi][nf];
#pragma unroll
      for (int r = 0; r < 4; ++r) {
        const int kk = kk0 + r;
        if (kk < L) {
          out_trunc[((size_t)b * L + kk) * C_ + c] = v[r];
        } else if (kk < L2) {
          out_state[((size_t)b * L + (kk - L)) * C_ + c] = (float)(f16)v[r];
        }
      }
    }
  }
}

// ---------------- launch ----------------------------------------------------
extern "C" void kernel_launch(void* const* d_in, const int* in_sizes, int n_in,
                              void* d_out, int out_size, void* d_ws, size_t ws_size,
                              hipStream_t stream) {
  (void)in_sizes; (void)n_in;
  const float* x = (const float*)d_in[0];

  // out = [state (64,L,1024) fp16-rounded | x_dct_trunc (64,L,1024)], both f32
  const int L = out_size / (2 * B_ * C_);
  const int mtiles = (2 * L + 255) / 256;
  float* out_state = (float*)d_out;
  float* out_trunc = out_state + (size_t)B_ * L * C_;

  char* w = (char*)d_ws;
  const size_t SZ_XT = (size_t)B_ * C_ * KDIM * sizeof(f16);  // 75,497,472 B
  const size_t SZ_A  = (size_t)AROWS * KDIM * sizeof(f16);    //  1,474,560 B
  const size_t SZ_M  = (size_t)MPAD * KDIM * sizeof(f16);     //    737,280 B
  if (ws_size < SZ_XT + SZ_A + 4 * SZ_M) return;  // ~80 MB scratch

  f16* XT   = (f16*)(w);
  f16* Astk = (f16*)(w + SZ_XT);
  f16* MTh  = (f16*)(w + SZ_XT + SZ_A);
  f16* MTl  = (f16*)(w + SZ_XT + SZ_A + 1 * SZ_M);
  f16* MiTh = (f16*)(w + SZ_XT + SZ_A + 2 * SZ_M);
  f16* MiTl = (f16*)(w + SZ_XT + SZ_A + 3 * SZ_M);

  gen_mats<<<dim3((AROWS * KDIM + 255) / 256, 3), 256, 0, stream>>>(
      Astk, MTh, MTl, MiTh, MiTl, L);
  gemm_G<<<dim3(MPAD / 128, MPAD / 128), 256, 0, stream>>>(
      MTh, MTl, MiTh, MiTl, Astk, L);
  transpose_f16<<<dim3(C_ / 64, T_ / 64, B_), 256, 0, stream>>>(x, XT);
  gemm256<<<dim3(C_ / 256, mtiles, B_), 512, 0, stream>>>(
      Astk, XT, out_trunc, out_state, L);
}

// Round 8
// 530.051 us; speedup vs baseline: 1.0278x; 1.0278x over previous
//
#include <hip/hip_runtime.h>
#include <hip/hip_bf16.h>

typedef _Float16 f16;
typedef _Float16 f16x4 __attribute__((ext_vector_type(4)));
typedef _Float16 f16x8 __attribute__((ext_vector_type(8)));
typedef float f32x4 __attribute__((ext_vector_type(4)));

#define B_    64
#define T_    576
#define C_    1024
#define KDIM  576     // K extent / row stride of all staged matrices
#define MPAD  640     // padded row count for matrix buffers

// async global->LDS, 16B per lane; LDS dest must be linear (base + lane*16)
__device__ __forceinline__ void gload_lds16(const void* g, void* l) {
  __builtin_amdgcn_global_load_lds(
      (__attribute__((address_space(1))) void*)(void*)g,
      (__attribute__((address_space(3))) void*)l, 16, 0, 0);
}

// ---------------- matrix generation (replicates jnp float32 op order) -------
// y=0: Mh  [640][576]  = M[k][t]   f16            (zero rows k>=576)
// y=1: MT  [640][576]  = M[l][t] at [t][l], hi/lo (zero rows t>=576)
// y=2: MiT [640][576]  = Mi[l][k] at [k][l], hi/lo (zero outside k<L,l<L)
__global__ void gen_mats(f16* __restrict__ Mh,
                         f16* __restrict__ MTh, f16* __restrict__ MTl,
                         f16* __restrict__ MiTh, f16* __restrict__ MiTl, int L) {
  int idx = blockIdx.x * 256 + threadIdx.x;
  if (idx >= MPAD * KDIM) return;
  int row = idx / KDIM;
  int col = idx - row * KDIM;
  const float pif = 3.14159265358979323846f;  // f32-rounded pi, as jnp uses
  float v = 0.0f;
  if (blockIdx.y == 0) {
    // M[k][t], k=row, t=col
    if (row < T_) {
      float a = pif * (float)(2 * col + 1);
      a = a * (float)row;
      a = a / 1152.0f;
      float s = (row == 0) ? sqrtf((float)(1.0 / 576.0)) : sqrtf((float)(2.0 / 576.0));
      v = s * cosf(a);
    }
    Mh[idx] = (f16)v;
  } else if (blockIdx.y == 1) {
    // MT[t][l] = M[l][t], t=row, l=col
    if (row < T_) {
      float a = pif * (float)(2 * row + 1);
      a = a * (float)col;
      a = a / 1152.0f;
      float s = (col == 0) ? sqrtf((float)(1.0 / 576.0)) : sqrtf((float)(2.0 / 576.0));
      v = s * cosf(a);
    }
    f16 h = (f16)v;
    MTh[idx] = h;
    MTl[idx] = (f16)(v - (float)h);
  } else {
    // MiT[k][l] = Mi[l][k], k=row, l=col; dct_mat(L)
    if (row < L && col < L) {
      float a = pif * (float)(2 * row + 1);
      a = a * (float)col;
      a = a / (float)(2 * L);
      float s = (col == 0) ? sqrtf((float)(1.0 / (double)L))
                           : sqrtf((float)(2.0 / (double)L));
      v = s * cosf(a);
    }
    f16 h = (f16)v;
    MiTh[idx] = h;
    MiTl[idx] = (f16)(v - (float)h);
  }
}

// ---------------- G = MiT . M_L  via hi/lo split MFMA (f32-accurate) --------
// D[m=t][n=k] = sum_l MT[t][l]*MiT[k][l]  ->  store G[k][t] f16 (t contiguous)
__global__ void gemm_G(const f16* __restrict__ gAh, const f16* __restrict__ gAl,
                       const f16* __restrict__ gBh, const f16* __restrict__ gBl,
                       f16* __restrict__ G) {
  __shared__ __align__(16) f16 sAh[128 * 32];
  __shared__ __align__(16) f16 sAl[128 * 32];
  __shared__ __align__(16) f16 sBh[128 * 32];
  __shared__ __align__(16) f16 sBl[128 * 32];
  const int tid = threadIdx.x, lane = tid & 63, wid = tid >> 6;
  const int m0 = blockIdx.y * 128, n0 = blockIdx.x * 128;
  const int wr = wid >> 1, wc = wid & 1;
  const int l15 = lane & 15, lg = lane >> 4;

  f32x4 acc[4][4];
#pragma unroll
  for (int i = 0; i < 4; ++i)
#pragma unroll
    for (int j = 0; j < 4; ++j) acc[i][j] = (f32x4){0.f, 0.f, 0.f, 0.f};

  for (int kt = 0; kt < KDIM; kt += 32) {
    __syncthreads();
#pragma unroll
    for (int it = 0; it < 2; ++it) {
      const int o = it * 4096 + tid * 16;
      const int r = o >> 6, cb = o & 63;
      gload_lds16((const char*)gAh + ((size_t)(m0 + r) * KDIM + kt) * 2 + cb, (char*)sAh + o);
      gload_lds16((const char*)gAl + ((size_t)(m0 + r) * KDIM + kt) * 2 + cb, (char*)sAl + o);
      gload_lds16((const char*)gBh + ((size_t)(n0 + r) * KDIM + kt) * 2 + cb, (char*)sBh + o);
      gload_lds16((const char*)gBl + ((size_t)(n0 + r) * KDIM + kt) * 2 + cb, (char*)sBl + o);
    }
    __syncthreads();

    f16x8 ah[4], al[4], bh[4], bl[4];
#pragma unroll
    for (int i = 0; i < 4; ++i) {
      const int ra = (wr * 64 + i * 16 + l15) * 32 + lg * 8;
      ah[i] = *(const f16x8*)&sAh[ra];
      al[i] = *(const f16x8*)&sAl[ra];
      const int rb = (wc * 64 + i * 16 + l15) * 32 + lg * 8;
      bh[i] = *(const f16x8*)&sBh[rb];
      bl[i] = *(const f16x8*)&sBl[rb];
    }
#pragma unroll
    for (int i = 0; i < 4; ++i)
#pragma unroll
      for (int j = 0; j < 4; ++j) {
        acc[i][j] = __builtin_amdgcn_mfma_f32_16x16x32_f16(ah[i], bh[j], acc[i][j], 0, 0, 0);
        acc[i][j] = __builtin_amdgcn_mfma_f32_16x16x32_f16(ah[i], bl[j], acc[i][j], 0, 0, 0);
        acc[i][j] = __builtin_amdgcn_mfma_f32_16x16x32_f16(al[i], bh[j], acc[i][j], 0, 0, 0);
      }
  }

#pragma unroll
  for (int i = 0; i < 4; ++i) {
    const int t4 = m0 + wr * 64 + i * 16 + lg * 4;  // 4 consecutive t
#pragma unroll
    for (int j = 0; j < 4; ++j) {
      const int k = n0 + wc * 64 + j * 16 + l15;
      if (t4 < T_) {  // t4..t4+3 all < 576 (t4 multiple of 4)
        f32x4 v = acc[i][j];
        f16x4 hv;
#pragma unroll
        for (int r = 0; r < 4; ++r) hv[r] = (f16)v[r];
        *(f16x4*)&G[(size_t)k * KDIM + t4] = hv;
      }
    }
  }
}

// ---------------- transpose + fp32 -> fp16 ----------------------------------
// x[b][t][c] (f32) -> XT[b][c][t] (f16)
__global__ void transpose_f16(const float* __restrict__ x, f16* __restrict__ XT) {
  __shared__ float tile[64][65];
  const int b = blockIdx.z;
  const int t0 = blockIdx.y * 64, c0 = blockIdx.x * 64;
  const int i = threadIdx.x;
  const float* xp = x + ((size_t)b * T_ + t0) * C_ + c0;
  const int lrow = i >> 4, lcq = (i & 15) * 4;
#pragma unroll
  for (int p = 0; p < 4; ++p) {
    int r = p * 16 + lrow;
    float4 v = *(const float4*)&xp[(size_t)r * C_ + lcq];
    tile[r][lcq + 0] = v.x; tile[r][lcq + 1] = v.y;
    tile[r][lcq + 2] = v.z; tile[r][lcq + 3] = v.w;
  }
  __syncthreads();
  const int tg = (i & 7) * 8, cl = i >> 3;  // cl in [0,32)
#pragma unroll
  for (int h = 0; h < 2; ++h) {
    int c = cl + h * 32;
    f16x8 o;
#pragma unroll
    for (int u = 0; u < 8; ++u) o[u] = (f16)tile[tg + u][c];
    *(f16x8*)&XT[((size_t)b * C_ + c0 + c) * T_ + t0 + tg] = o;
  }
}

// ---------------- merged main GEMM (m97-style 128x128 tile) -----------------
// stage0: trunc = M . x   stage1: state = G . x
// D[m=k][n=c] = sum_t A[k][t] * XT_b[c][t]
// XCD-grouping swizzle: all 80 blocks sharing one XT_b panel (8n x 5m x 2stage)
// land on ONE XCD (assumes linear-id % 8 = XCD round-robin; perf-only).
__global__ void gemm_main(const f16* __restrict__ gM, const f16* __restrict__ gG,
                          const f16* __restrict__ gXT,
                          float* __restrict__ out_trunc, float* __restrict__ out_state,
                          int L) {
  __shared__ __align__(16) f16 sA[128 * 32];
  __shared__ __align__(16) f16 sB[128 * 32];

  const int tid = threadIdx.x, lane = tid & 63, wid = tid >> 6;

  // ---- block-id swizzle: j -> (xcd, s); b = xcd*8 + s/80; inner = s%80 ----
  const int j = blockIdx.x + 8 * (blockIdx.y + 5 * blockIdx.z);  // 0..5119
  const int xcd = j & 7, s = j >> 3;          // s in [0, 640)
  const int b = xcd * 8 + s / 80;             // 64 batches
  const int inner = s % 80;                   // (stage, n, m)
  const int stage = inner & 1;
  const int nt = (inner >> 1) & 7;            // 8 n-tiles
  const int mt = inner >> 4;                  // 5 m-tiles

  const int m0 = mt * 128, n0 = nt * 128;
  const int wr = wid >> 1, wc = wid & 1;
  const int l15 = lane & 15, lg = lane >> 4;

  const f16* gA = stage ? gG : gM;
  const f16* bb = gXT + (size_t)b * C_ * KDIM;

  f32x4 acc[4][4];
#pragma unroll
  for (int i = 0; i < 4; ++i)
#pragma unroll
    for (int j2 = 0; j2 < 4; ++j2) acc[i][j2] = (f32x4){0.f, 0.f, 0.f, 0.f};

  for (int kt = 0; kt < KDIM; kt += 32) {
    __syncthreads();
#pragma unroll
    for (int it = 0; it < 2; ++it) {
      const int o = it * 4096 + tid * 16;  // byte offset in 8KB tile
      const int r = o >> 6, cb = o & 63;   // row / byte-in-row (32 f16 = 64B)
      gload_lds16((const char*)gA + ((size_t)(m0 + r) * KDIM + kt) * 2 + cb,
                  (char*)sA + o);
      gload_lds16((const char*)bb + ((size_t)(n0 + r) * KDIM + kt) * 2 + cb,
                  (char*)sB + o);
    }
    __syncthreads();

    f16x8 af[4], bf[4];
#pragma unroll
    for (int i = 0; i < 4; ++i) {
      af[i] = *(const f16x8*)&sA[(wr * 64 + i * 16 + l15) * 32 + lg * 8];
      bf[i] = *(const f16x8*)&sB[(wc * 64 + i * 16 + l15) * 32 + lg * 8];
    }
#pragma unroll
    for (int i = 0; i < 4; ++i)
#pragma unroll
      for (int j2 = 0; j2 < 4; ++j2)
        acc[i][j2] = __builtin_amdgcn_mfma_f32_16x16x32_f16(af[i], bf[j2], acc[i][j2], 0, 0, 0);
  }

  float* outp = stage ? out_state : out_trunc;
#pragma unroll
  for (int i = 0; i < 4; ++i) {
    const int k0 = m0 + wr * 64 + i * 16 + lg * 4;  // 4 consecutive output rows
#pragma unroll
    for (int j2 = 0; j2 < 4; ++j2) {
      const int c = n0 + wc * 64 + j2 * 16 + l15;
      f32x4 v = acc[i][j2];
#pragma unroll
      for (int r = 0; r < 4; ++r) {
        const int k = k0 + r;
        if (k < L) {
          float val = v[r];
          if (stage) val = (float)(f16)val;  // fp16 RTNE like .astype(float16)
          outp[((size_t)b * L + k) * C_ + c] = val;
        }
      }
    }
  }
}

// ---------------- launch ----------------------------------------------------
extern "C" void kernel_launch(void* const* d_in, const int* in_sizes, int n_in,
                              void* d_out, int out_size, void* d_ws, size_t ws_size,
                              hipStream_t stream) {
  (void)in_sizes; (void)n_in;
  const float* x = (const float*)d_in[0];

  // out = [state (64,L,1024) fp16-rounded | x_dct_trunc (64,L,1024)], both f32
  const int L = out_size / (2 * B_ * C_);
  float* out_state = (float*)d_out;
  float* out_trunc = out_state + (size_t)B_ * L * C_;

  char* w = (char*)d_ws;
  const size_t SZ_XT = (size_t)B_ * C_ * KDIM * sizeof(f16);  // 75,497,472 B
  const size_t SZ_M  = (size_t)MPAD * KDIM * sizeof(f16);     //    737,280 B
  if (ws_size < SZ_XT + 6 * SZ_M) return;  // ~80 MB scratch

  f16* XT   = (f16*)(w);
  f16* Mh   = (f16*)(w + SZ_XT);
  f16* Gh   = (f16*)(w + SZ_XT + 1 * SZ_M);
  f16* MTh  = (f16*)(w + SZ_XT + 2 * SZ_M);
  f16* MTl  = (f16*)(w + SZ_XT + 3 * SZ_M);
  f16* MiTh = (f16*)(w + SZ_XT + 4 * SZ_M);
  f16* MiTl = (f16*)(w + SZ_XT + 5 * SZ_M);

  gen_mats<<<dim3((MPAD * KDIM + 255) / 256, 3), 256, 0, stream>>>(
      Mh, MTh, MTl, MiTh, MiTl, L);
  gemm_G<<<dim3(MPAD / 128, MPAD / 128), 256, 0, stream>>>(
      MTh, MTl, MiTh, MiTl, Gh);
  transpose_f16<<<dim3(C_ / 64, T_ / 64, B_), 256, 0, stream>>>(x, XT);
  // grid shape kept (8,5,128); true (b,stage,n,m) decoded via swizzle in-kernel
  gemm_main<<<dim3(C_ / 128, 5, 2 * B_), 256, 0, stream>>>(
      Mh, Gh, XT, out_trunc, out_state, L);
}

// Round 9
// 523.802 us; speedup vs baseline: 1.0401x; 1.0119x over previous
//
#include <hip/hip_runtime.h>
#include <hip/hip_bf16.h>

typedef _Float16 f16;
typedef _Float16 f16x4 __attribute__((ext_vector_type(4)));
typedef _Float16 f16x8 __attribute__((ext_vector_type(8)));
typedef float f32x4 __attribute__((ext_vector_type(4)));

#define B_    64
#define T_    576
#define C_    1024
#define KDIM  576     // K extent / row stride of all staged matrices
#define MPAD  640     // padded row count for matrix buffers
#define TRBLK (16 * 9 * 64)   // transpose blocks in fused prep kernel

// async global->LDS, 16B per lane; LDS dest must be linear (base + lane*16)
__device__ __forceinline__ void gload_lds16(const void* g, void* l) {
  __builtin_amdgcn_global_load_lds(
      (__attribute__((address_space(1))) void*)(void*)g,
      (__attribute__((address_space(3))) void*)l, 16, 0, 0);
}

// ---------------- fused prep: x-transpose + matrix generation ---------------
// blocks [0, TRBLK):            x[b][t][c] f32 -> XT[b][c][t] f16
// blocks [TRBLK, TRBLK+3*1440): gen M / MT(hi,lo) / MiT(hi,lo), jnp f32 op order
__global__ void prep(const float* __restrict__ x, f16* __restrict__ XT,
                     f16* __restrict__ Mh,
                     f16* __restrict__ MTh, f16* __restrict__ MTl,
                     f16* __restrict__ MiTh, f16* __restrict__ MiTl, int L) {
  __shared__ float tile[64][65];
  const int tb = blockIdx.x;
  if (tb < TRBLK) {
    // ---- transpose: 144 blocks per batch (16 c-tiles x 9 t-tiles) ----
    const int b = tb / 144, rem = tb % 144;
    const int c0 = (rem & 15) * 64, t0 = (rem >> 4) * 64;
    const int i = threadIdx.x;
    const float* xp = x + ((size_t)b * T_ + t0) * C_ + c0;
    const int lrow = i >> 4, lcq = (i & 15) * 4;
#pragma unroll
    for (int p = 0; p < 4; ++p) {
      int r = p * 16 + lrow;
      float4 v = *(const float4*)&xp[(size_t)r * C_ + lcq];
      tile[r][lcq + 0] = v.x; tile[r][lcq + 1] = v.y;
      tile[r][lcq + 2] = v.z; tile[r][lcq + 3] = v.w;
    }
    __syncthreads();
    const int tg = (i & 7) * 8, cl = i >> 3;  // cl in [0,32)
#pragma unroll
    for (int h = 0; h < 2; ++h) {
      int c = cl + h * 32;
      f16x8 o;
#pragma unroll
      for (int u = 0; u < 8; ++u) o[u] = (f16)tile[tg + u][c];
      *(f16x8*)&XT[((size_t)b * C_ + c0 + c) * T_ + t0 + tg] = o;
    }
  } else {
    // ---- matrix gen: y = 0 (M), 1 (MT hi/lo), 2 (MiT hi/lo) ----
    const int g = tb - TRBLK;
    const int y = g / 1440;
    const int idx = (g - y * 1440) * 256 + threadIdx.x;
    if (idx >= MPAD * KDIM) return;
    const int row = idx / KDIM;
    const int col = idx - row * KDIM;
    const float pif = 3.14159265358979323846f;  // f32-rounded pi, as jnp uses
    float v = 0.0f;
    if (y == 0) {
      // M[k][t], k=row, t=col
      if (row < T_) {
        float a = pif * (float)(2 * col + 1);
        a = a * (float)row;
        a = a / 1152.0f;
        float s = (row == 0) ? sqrtf((float)(1.0 / 576.0)) : sqrtf((float)(2.0 / 576.0));
        v = s * cosf(a);
      }
      Mh[idx] = (f16)v;
    } else if (y == 1) {
      // MT[t][l] = M[l][t], t=row, l=col
      if (row < T_) {
        float a = pif * (float)(2 * row + 1);
        a = a * (float)col;
        a = a / 1152.0f;
        float s = (col == 0) ? sqrtf((float)(1.0 / 576.0)) : sqrtf((float)(2.0 / 576.0));
        v = s * cosf(a);
      }
      f16 h = (f16)v;
      MTh[idx] = h;
      MTl[idx] = (f16)(v - (float)h);
    } else {
      // MiT[k][l] = Mi[l][k], k=row, l=col; dct_mat(L)
      if (row < L && col < L) {
        float a = pif * (float)(2 * row + 1);
        a = a * (float)col;
        a = a / (float)(2 * L);
        float s = (col == 0) ? sqrtf((float)(1.0 / (double)L))
                             : sqrtf((float)(2.0 / (double)L));
        v = s * cosf(a);
      }
      f16 h = (f16)v;
      MiTh[idx] = h;
      MiTl[idx] = (f16)(v - (float)h);
    }
  }
}

// ---------------- G = MiT . M_L  via hi/lo split MFMA (f32-accurate) --------
// D[m=t][n=k] = sum_l MT[t][l]*MiT[k][l]  ->  store G[k][t] f16 (t contiguous)
__global__ void gemm_G(const f16* __restrict__ gAh, const f16* __restrict__ gAl,
                       const f16* __restrict__ gBh, const f16* __restrict__ gBl,
                       f16* __restrict__ G) {
  __shared__ __align__(16) f16 sAh[128 * 32];
  __shared__ __align__(16) f16 sAl[128 * 32];
  __shared__ __align__(16) f16 sBh[128 * 32];
  __shared__ __align__(16) f16 sBl[128 * 32];
  const int tid = threadIdx.x, lane = tid & 63, wid = tid >> 6;
  const int m0 = blockIdx.y * 128, n0 = blockIdx.x * 128;
  const int wr = wid >> 1, wc = wid & 1;
  const int l15 = lane & 15, lg = lane >> 4;

  f32x4 acc[4][4];
#pragma unroll
  for (int i = 0; i < 4; ++i)
#pragma unroll
    for (int j = 0; j < 4; ++j) acc[i][j] = (f32x4){0.f, 0.f, 0.f, 0.f};

  for (int kt = 0; kt < KDIM; kt += 32) {
    __syncthreads();
#pragma unroll
    for (int it = 0; it < 2; ++it) {
      const int o = it * 4096 + tid * 16;
      const int r = o >> 6, cb = o & 63;
      gload_lds16((const char*)gAh + ((size_t)(m0 + r) * KDIM + kt) * 2 + cb, (char*)sAh + o);
      gload_lds16((const char*)gAl + ((size_t)(m0 + r) * KDIM + kt) * 2 + cb, (char*)sAl + o);
      gload_lds16((const char*)gBh + ((size_t)(n0 + r) * KDIM + kt) * 2 + cb, (char*)sBh + o);
      gload_lds16((const char*)gBl + ((size_t)(n0 + r) * KDIM + kt) * 2 + cb, (char*)sBl + o);
    }
    __syncthreads();

    f16x8 ah[4], al[4], bh[4], bl[4];
#pragma unroll
    for (int i = 0; i < 4; ++i) {
      const int ra = (wr * 64 + i * 16 + l15) * 32 + lg * 8;
      ah[i] = *(const f16x8*)&sAh[ra];
      al[i] = *(const f16x8*)&sAl[ra];
      const int rb = (wc * 64 + i * 16 + l15) * 32 + lg * 8;
      bh[i] = *(const f16x8*)&sBh[rb];
      bl[i] = *(const f16x8*)&sBl[rb];
    }
#pragma unroll
    for (int i = 0; i < 4; ++i)
#pragma unroll
      for (int j = 0; j < 4; ++j) {
        acc[i][j] = __builtin_amdgcn_mfma_f32_16x16x32_f16(ah[i], bh[j], acc[i][j], 0, 0, 0);
        acc[i][j] = __builtin_amdgcn_mfma_f32_16x16x32_f16(ah[i], bl[j], acc[i][j], 0, 0, 0);
        acc[i][j] = __builtin_amdgcn_mfma_f32_16x16x32_f16(al[i], bh[j], acc[i][j], 0, 0, 0);
      }
  }

#pragma unroll
  for (int i = 0; i < 4; ++i) {
    const int t4 = m0 + wr * 64 + i * 16 + lg * 4;  // 4 consecutive t
#pragma unroll
    for (int j = 0; j < 4; ++j) {
      const int k = n0 + wc * 64 + j * 16 + l15;
      if (t4 < T_) {  // t4..t4+3 all < 576 (t4 multiple of 4)
        f32x4 v = acc[i][j];
        f16x4 hv;
#pragma unroll
        for (int r = 0; r < 4; ++r) hv[r] = (f16)v[r];
        *(f16x4*)&G[(size_t)k * KDIM + t4] = hv;
      }
    }
  }
}

// ---------------- merged main GEMM, 128x128 tile, BK=64 ---------------------
// stage0: trunc = M . x   stage1: state = G . x
// D[m=k][n=c] = sum_t A[k][t] * XT_b[c][t]
// BK=64: 9 staged K-tiles (vs 18) -> half the vmcnt(0)+barrier drains.
// Accumulation order identical to BK=32 version (ks=0 then ks=1) -> bit-same.
__global__ void gemm_main(const f16* __restrict__ gM, const f16* __restrict__ gG,
                          const f16* __restrict__ gXT,
                          float* __restrict__ out_trunc, float* __restrict__ out_state,
                          int L) {
  __shared__ __align__(16) f16 sA[128 * 64];  // 16 KB
  __shared__ __align__(16) f16 sB[128 * 64];  // 16 KB

  const int tid = threadIdx.x, lane = tid & 63, wid = tid >> 6;
  const int z = blockIdx.z, b = z >> 1, stage = z & 1;
  const int m0 = blockIdx.y * 128, n0 = blockIdx.x * 128;
  const int wr = wid >> 1, wc = wid & 1;
  const int l15 = lane & 15, lg = lane >> 4;

  const f16* gA = stage ? gG : gM;
  const f16* bb = gXT + (size_t)b * C_ * KDIM;

  f32x4 acc[4][4];
#pragma unroll
  for (int i = 0; i < 4; ++i)
#pragma unroll
    for (int j = 0; j < 4; ++j) acc[i][j] = (f32x4){0.f, 0.f, 0.f, 0.f};

  for (int kt = 0; kt < KDIM; kt += 64) {
    __syncthreads();
#pragma unroll
    for (int it = 0; it < 4; ++it) {
      const int o = it * 4096 + tid * 16;  // byte offset in 16KB tile
      const int r = o >> 7, cb = o & 127;  // row / byte-in-row (64 f16 = 128B)
      gload_lds16((const char*)gA + (size_t)(m0 + r) * (KDIM * 2) + kt * 2 + cb,
                  (char*)sA + o);
      gload_lds16((const char*)bb + (size_t)(n0 + r) * (KDIM * 2) + kt * 2 + cb,
                  (char*)sB + o);
    }
    __syncthreads();  // compiler emits vmcnt(0) drain here (once per 64-K now)

#pragma unroll
    for (int ks = 0; ks < 2; ++ks) {
      f16x8 af[4], bf[4];
#pragma unroll
      for (int i = 0; i < 4; ++i) {
        af[i] = *(const f16x8*)&sA[(wr * 64 + i * 16 + l15) * 64 + ks * 32 + lg * 8];
        bf[i] = *(const f16x8*)&sB[(wc * 64 + i * 16 + l15) * 64 + ks * 32 + lg * 8];
      }
#pragma unroll
      for (int i = 0; i < 4; ++i)
#pragma unroll
        for (int j = 0; j < 4; ++j)
          acc[i][j] = __builtin_amdgcn_mfma_f32_16x16x32_f16(af[i], bf[j], acc[i][j], 0, 0, 0);
    }
  }

  float* outp = stage ? out_state : out_trunc;
#pragma unroll
  for (int i = 0; i < 4; ++i) {
    const int k0 = m0 + wr * 64 + i * 16 + lg * 4;  // 4 consecutive output rows
#pragma unroll
    for (int j = 0; j < 4; ++j) {
      const int c = n0 + wc * 64 + j * 16 + l15;
      f32x4 v = acc[i][j];
#pragma unroll
      for (int r = 0; r < 4; ++r) {
        const int k = k0 + r;
        if (k < L) {
          float val = v[r];
          if (stage) val = (float)(f16)val;  // fp16 RTNE like .astype(float16)
          outp[((size_t)b * L + k) * C_ + c] = val;
        }
      }
    }
  }
}

// ---------------- launch ----------------------------------------------------
extern "C" void kernel_launch(void* const* d_in, const int* in_sizes, int n_in,
                              void* d_out, int out_size, void* d_ws, size_t ws_size,
                              hipStream_t stream) {
  (void)in_sizes; (void)n_in;
  const float* x = (const float*)d_in[0];

  // out = [state (64,L,1024) fp16-rounded | x_dct_trunc (64,L,1024)], both f32
  const int L = out_size / (2 * B_ * C_);
  float* out_state = (float*)d_out;
  float* out_trunc = out_state + (size_t)B_ * L * C_;

  char* w = (char*)d_ws;
  const size_t SZ_XT = (size_t)B_ * C_ * KDIM * sizeof(f16);  // 75,497,472 B
  const size_t SZ_M  = (size_t)MPAD * KDIM * sizeof(f16);     //    737,280 B
  if (ws_size < SZ_XT + 6 * SZ_M) return;  // ~80 MB scratch

  f16* XT   = (f16*)(w);
  f16* Mh   = (f16*)(w + SZ_XT);
  f16* Gh   = (f16*)(w + SZ_XT + 1 * SZ_M);
  f16* MTh  = (f16*)(w + SZ_XT + 2 * SZ_M);
  f16* MTl  = (f16*)(w + SZ_XT + 3 * SZ_M);
  f16* MiTh = (f16*)(w + SZ_XT + 4 * SZ_M);
  f16* MiTl = (f16*)(w + SZ_XT + 5 * SZ_M);

  prep<<<TRBLK + 3 * 1440, 256, 0, stream>>>(
      x, XT, Mh, MTh, MTl, MiTh, MiTl, L);
  gemm_G<<<dim3(MPAD / 128, MPAD / 128), 256, 0, stream>>>(
      MTh, MTl, MiTh, MiTl, Gh);
  gemm_main<<<dim3(C_ / 128, 5, 2 * B_), 256, 0, stream>>>(
      Mh, Gh, XT, out_trunc, out_state, L);
}